// Round 15
// baseline (810.587 us; speedup 1.0000x reference)
//
#include <hip/hip_runtime.h>
#include <hip/hip_bf16.h>
#include <stdint.h>

#define TOKENS 8192
#define NOUT   4096
#define KIN    4096

#define BM 256
#define BN 256
#define BK 64
#define NT (KIN / BK)   // 64 K-tiles

typedef __attribute__((ext_vector_type(8))) short bf16x8;
typedef __attribute__((ext_vector_type(4))) float f32x4;

__device__ __forceinline__ uint32_t rotl32(uint32_t x, int r) {
  return (x << r) | (x >> (32 - r));
}

__device__ __forceinline__ uint16_t f2bf_rne(float f) {
  uint32_t u = __float_as_uint(f);
  u += 0x7FFFu + ((u >> 16) & 1u);
  return (uint16_t)(u >> 16);
}

// Threefry-2x32, 20 rounds — JAX PRNG core.
__device__ __forceinline__ void threefry2x32(uint32_t k0, uint32_t k1,
                                             uint32_t c0, uint32_t c1,
                                             uint32_t& o0, uint32_t& o1) {
  uint32_t ks2 = 0x1BD11BDAu ^ k0 ^ k1;
  uint32_t x0 = c0 + k0;
  uint32_t x1 = c1 + k1;
#define TFR(r) { x0 += x1; x1 = rotl32(x1, (r)); x1 ^= x0; }
  TFR(13) TFR(15) TFR(26) TFR(6)
  x0 += k1;  x1 += ks2 + 1u;
  TFR(17) TFR(29) TFR(16) TFR(24)
  x0 += ks2; x1 += k0 + 2u;
  TFR(13) TFR(15) TFR(26) TFR(6)
  x0 += k0;  x1 += k1 + 3u;
  TFR(17) TFR(29) TFR(16) TFR(24)
  x0 += k1;  x1 += ks2 + 4u;
  TFR(13) TFR(15) TFR(26) TFR(6)
  x0 += ks2; x1 += k0 + 5u;
#undef TFR
  o0 = x0; o1 = x1;
}

// Fused prep, interleaved 4:1 hydrate:convert (r13, verified win).
__global__ void prep_kernel(const float* __restrict__ x,
                            uint16_t* __restrict__ xb,
                            uint16_t* __restrict__ W,
                            const int* __restrict__ seed_ptr) {
  uint32_t b = blockIdx.x;
  uint32_t g = b / 5u, r = b % 5u;
  if (r < 4u) {
    uint32_t k1 = (uint32_t)(*seed_ptr);                  // key = (0, seed)
    uint32_t j = (g * 4u + r) * 256u + threadIdx.x;       // 0 .. 2^24-1
    uint32_t o0, o1;
    threefry2x32(0u, k1, 0u, j, o0, o1);
    uint32_t bits = o0 ^ o1;
    const float scale = 0.03125f;
    const float mn    = -0.015625f;
    float f = __uint_as_float((bits >> 9) | 0x3F800000u) - 1.0f;
    float v = fmaxf(mn, f * scale + mn);
    W[j] = f2bf_rne(v);
  } else {
    uint32_t base = (g * 256u + threadIdx.x) * 8u;
    f32x4 a = *(const f32x4*)(x + base);
    f32x4 c = *(const f32x4*)(x + base + 4);
    union { uint16_t u[8]; bf16x8 v; } rr;
    rr.u[0] = f2bf_rne(a[0]); rr.u[1] = f2bf_rne(a[1]);
    rr.u[2] = f2bf_rne(a[2]); rr.u[3] = f2bf_rne(a[3]);
    rr.u[4] = f2bf_rne(c[0]); rr.u[5] = f2bf_rne(c[1]);
    rr.u[6] = f2bf_rne(c[2]); rr.u[7] = f2bf_rne(c[3]);
    *(bf16x8*)(xb + base) = rr.v;
  }
}

// ---------------------------------------------------------------------------
// 256x256 / BK=64 / 8-wave / 16x16x32 — ONE barrier per K-tile with
// PARITY-DESYNCHRONIZED quadrant order. Even waves: (0,0),(0,1),(1,1),(1,0);
// odd waves: (1,1),(1,0),(0,0),(0,1). Half the block computes MFMA while the
// other half issues ds_reads -> LDS-port time (~2304 cyc/CU/tile) hides
// under MFMA (~2483 cyc) instead of serializing after it (r12-r14 lockstep
// measured ~4100 cyc = the sum).
//
// Per tile kt (buf = kt&1):
//   VMW(0)            // my 8 stage-loads of kt (issued last tile) landed
//   s_barrier         // all waves done reading buf^1 (their last MFMA's
//                     // LKW(0) preceded arrival) + kt published
//   stage 4 halves of kt+1 -> buf^1   (post-barrier => WAR-safe; drained
//                                      by NEXT tile's VMW(0), ~2500 cyc)
//   parity-ordered quadrants on buf: per quadrant, reads (SB0-pinned
//   s0/s1 groups) + counted LKW + 8/8 MFMA (r13-verified counts);
//   4th quadrant uses cached operands.
// Liveness per parity: single af set (A0 then A1, or A1 then A0) + bv0 +
// bv1 = 64 operand VGPRs. Skew bound < 1 tile (the barrier).
// Tail: tile 63 stages nothing. Prologue: stage kt0 -> buf0, then loop
// (first VMW(0) exposes one HBM latency — once).
// LDS swizzle: linear gload_lds dest + inverse-swizzled global source;
// reads XOR ((row&7)<<4); 0 bank conflicts (r5-r14).
// ---------------------------------------------------------------------------
__global__ __launch_bounds__(512, 2)
void gemm_bias_kernel(const uint16_t* __restrict__ A,   // x  bf16 [TOKENS][KIN]
                      const uint16_t* __restrict__ B,   // W  bf16 [NOUT][KIN]
                      const float* __restrict__ bias,
                      float* __restrict__ C) {
  __shared__ uint16_t smem[2][2][16384];   // [buf][A=0/B=1][32KB] = 128 KiB

  const int nwgn = NOUT / BN;                 // 16
  const int nwg  = (TOKENS / BM) * nwgn;      // 512 (divisible by 8)
  int bid = blockIdx.x;
  int cpx = nwg >> 3;
  int swzb = (bid & 7) * cpx + (bid >> 3);    // bijective XCD swizzle
  int tm = (swzb / nwgn) * BM;
  int tn = (swzb % nwgn) * BN;

  const int t    = threadIdx.x;
  const int lane = t & 63;
  const int wid  = t >> 6;       // 0..7
  const int wm   = wid >> 2;     // 0..1
  const int wn   = wid & 3;      // 0..3
  const int fr   = lane & 15;
  const int fq   = lane >> 4;
  const bool evenW = (wid & 1) == 0;          // wave-uniform parity

  const int swzRd = (lane & 7) << 4;                    // frag-read byte XOR
  const int lsw   = ((lane & 7) ^ (lane >> 3)) << 4;    // stage src byte offset

  // loop-carried stage source pointers (advanced +256 B per 2-tile iter)
  const char* sA  = (const char*)(A + (size_t)(tm + wid * 16 + (lane >> 3)) * KIN) + lsw;
  const char* sB  = (const char*)(B + (size_t)(tn + wid * 16 + (lane >> 3)) * KIN) + lsw;
  const char* sA1 = sA + (size_t)128 * KIN * 2;   // +128 rows (half 1)
  const char* sB1 = sB + (size_t)128 * KIN * 2;

  char* const dstB = (char*)&smem[0][0][0] + wid * 2048 + lane * 16;

  f32x4 acc[8][4] = {};
  bf16x8 af[2][4], bv0[2][2], bv1[2][2];

  auto stage2 = [&](const char* src, char* dst) {
    __builtin_amdgcn_global_load_lds(
        (const __attribute__((address_space(1))) void*)src,
        (__attribute__((address_space(3))) void*)dst, 16, 0, 0);
    __builtin_amdgcn_global_load_lds(
        (const __attribute__((address_space(1))) void*)(src + (size_t)8 * KIN * 2),
        (__attribute__((address_space(3))) void*)(dst + 1024), 16, 0, 0);
  };

#define VMW(N) asm volatile("s_waitcnt vmcnt(" #N ")" ::: "memory")
#define LKW(N) asm volatile("s_waitcnt lgkmcnt(" #N ")" ::: "memory")
#define SB0    __builtin_amdgcn_sched_barrier(0)
#define PRI(p) __builtin_amdgcn_s_setprio(p)

// 4 ds_read_b128: af[S][0..3] of A-half MH, k-group S
#define RD_AS(BUFI, MH, S)                                                     \
    _Pragma("unroll")                                                          \
    for (int i_ = 0; i_ < 4; ++i_)                                             \
      af[S][i_] = *(const bf16x8*)((const char*)&smem[BUFI][0][0] +            \
          (wm * 64 + (MH) * 128 + i_ * 16 + fr) * 128 +                        \
          ((((S) << 6) | (fq << 4)) ^ swzRd));

// 2 ds_read_b128: BV[S][0..1] of B-half NH, k-group S
#define RD_BS(BUFI, BV, NH, S)                                                 \
    _Pragma("unroll")                                                          \
    for (int j_ = 0; j_ < 2; ++j_)                                             \
      BV[S][j_] = *(const bf16x8*)((const char*)&smem[BUFI][1][0] +            \
          (wn * 32 + (NH) * 128 + j_ * 16 + fr) * 128 +                        \
          ((((S) << 6) | (fq << 4)) ^ swzRd));

// 8 MFMA: k-group S of quadrant (MH,NH)
#define MF8(MH, NH, BV, S)                                                     \
    _Pragma("unroll")                                                          \
    for (int i_ = 0; i_ < 4; ++i_)                                             \
      _Pragma("unroll")                                                        \
      for (int j_ = 0; j_ < 2; ++j_)                                           \
        acc[(MH) * 4 + i_][(NH) * 2 + j_] =                                    \
            __builtin_amdgcn_mfma_f32_16x16x32_bf16(                           \
                af[S][i_], BV[S][j_], acc[(MH) * 4 + i_][(NH) * 2 + j_],       \
                0, 0, 0);

  // One K-tile. OFF = byte k-offset of kt+1 relative to current pointers.
  // MODE: 0 = stage kt+1; 1 = last tile (no stages).
#define KTILE(BUF, OFF, MODE)                                                  \
  {                                                                            \
    VMW(0);                                                                    \
    __builtin_amdgcn_s_barrier();                                              \
    if ((MODE) == 0) {                                                         \
      stage2(sA  + (OFF), dstB + ((BUF) ^ 1) * 65536);                         \
      stage2(sB  + (OFF), dstB + ((BUF) ^ 1) * 65536 + 32768);                 \
      stage2(sA1 + (OFF), dstB + ((BUF) ^ 1) * 65536 + 16384);                 \
      stage2(sB1 + (OFF), dstB + ((BUF) ^ 1) * 65536 + 49152);                 \
    }                                                                          \
    if (evenW) {                                                               \
      /* q00 */                                                                \
      RD_AS(BUF, 0, 0) RD_BS(BUF, bv0, 0, 0)                                   \
      SB0;                                                                     \
      RD_AS(BUF, 0, 1) RD_BS(BUF, bv0, 0, 1)                                   \
      SB0;                                                                     \
      LKW(6); SB0; PRI(1); MF8(0, 0, bv0, 0)                                   \
      LKW(0); SB0; MF8(0, 0, bv0, 1) PRI(0);                                   \
      /* q01 */                                                                \
      RD_BS(BUF, bv1, 1, 0)                                                    \
      SB0;                                                                     \
      RD_BS(BUF, bv1, 1, 1)                                                    \
      SB0;                                                                     \
      LKW(2); SB0; PRI(1); MF8(0, 1, bv1, 0)                                   \
      LKW(0); SB0; MF8(0, 1, bv1, 1) PRI(0);                                   \
      /* q11 */                                                                \
      RD_AS(BUF, 1, 0)                                                         \
      SB0;                                                                     \
      RD_AS(BUF, 1, 1)                                                         \
      SB0;                                                                     \
      LKW(4); SB0; PRI(1); MF8(1, 1, bv1, 0)                                   \
      LKW(0); SB0; MF8(1, 1, bv1, 1) PRI(0);                                   \
      /* q10 cached */                                                         \
      PRI(1); MF8(1, 0, bv0, 0) MF8(1, 0, bv0, 1) PRI(0);                      \
    } else {                                                                   \
      /* q11 */                                                                \
      RD_AS(BUF, 1, 0) RD_BS(BUF, bv1, 1, 0)                                   \
      SB0;                                                                     \
      RD_AS(BUF, 1, 1) RD_BS(BUF, bv1, 1, 1)                                   \
      SB0;                                                                     \
      LKW(6); SB0; PRI(1); MF8(1, 1, bv1, 0)                                   \
      LKW(0); SB0; MF8(1, 1, bv1, 1) PRI(0);                                   \
      /* q10 */                                                                \
      RD_BS(BUF, bv0, 0, 0)                                                    \
      SB0;                                                                     \
      RD_BS(BUF, bv0, 0, 1)                                                    \
      SB0;                                                                     \
      LKW(2); SB0; PRI(1); MF8(1, 0, bv0, 0)                                   \
      LKW(0); SB0; MF8(1, 0, bv0, 1) PRI(0);                                   \
      /* q00 */                                                                \
      RD_AS(BUF, 0, 0)                                                         \
      SB0;                                                                     \
      RD_AS(BUF, 0, 1)                                                         \
      SB0;                                                                     \
      LKW(4); SB0; PRI(1); MF8(0, 0, bv0, 0)                                   \
      LKW(0); SB0; MF8(0, 0, bv0, 1) PRI(0);                                   \
      /* q01 cached */                                                         \
      PRI(1); MF8(0, 1, bv1, 0) MF8(0, 1, bv1, 1) PRI(0);                      \
    }                                                                          \
  }

  // Prologue: stage kt0 -> buf0 (first tile's VMW(0) absorbs the latency).
  stage2(sA,  dstB);
  stage2(sB,  dstB + 32768);
  stage2(sA1, dstB + 16384);
  stage2(sB1, dstB + 49152);

  for (int it = 0; it < (NT - 2) / 2; ++it) {   // tiles 0..61
    KTILE(0, 128, 0)
    KTILE(1, 256, 0)
    sA += 256; sB += 256; sA1 += 256; sB1 += 256;
  }
  KTILE(0, 128, 0)   // tile 62: stages kt63 -> buf1
  KTILE(1, 0, 1)     // tile 63: no stages

#undef KTILE
#undef MF8
#undef RD_BS
#undef RD_AS
#undef PRI
#undef SB0
#undef LKW
#undef VMW

  // Epilogue: D row = fq*4 + rr, col = fr (m89/m91-verified), fused bias.
#pragma unroll
  for (int nj = 0; nj < 4; ++nj) {
    const int nh = nj >> 1, j = nj & 1;
    const int col = tn + wn * 32 + nh * 128 + j * 16 + fr;
    const float bvs = bias[col];
#pragma unroll
    for (int mi = 0; mi < 8; ++mi) {
      const int mh = mi >> 2, i = mi & 3;
      const int row0 = tm + wm * 64 + mh * 128 + i * 16 + fq * 4;
#pragma unroll
      for (int rr = 0; rr < 4; ++rr)
        C[(size_t)(row0 + rr) * NOUT + col] = acc[mi][nj][rr] + bvs;
    }
  }
}

extern "C" void kernel_launch(void* const* d_in, const int* in_sizes, int n_in,
                              void* d_out, int out_size, void* d_ws, size_t ws_size,
                              hipStream_t stream) {
  const float* x    = (const float*)d_in[0];   // [8192][4096] fp32
  const float* bias = (const float*)d_in[1];   // [4096] fp32
  const int*   seed = (const int*)d_in[2];     // [1] int
  float* y = (float*)d_out;                    // [8192][4096] fp32

  // workspace: W bf16 (32 MB) | x bf16 (64 MB) — 96 MB, proven available
  uint16_t* Wb = (uint16_t*)d_ws;
  uint16_t* Xb = Wb + (size_t)NOUT * KIN;

  prep_kernel<<<81920, 256, 0, stream>>>(x, Xb, Wb, seed);

  const int grid = (TOKENS / BM) * (NOUT / BN);   // 512
  gemm_bias_kernel<<<grid, 512, 0, stream>>>(Xb, Wb, bias, y);
}

// Round 17
// 251.060 us; speedup vs baseline: 3.2287x; 3.2287x over previous
//
#include <hip/hip_runtime.h>
#include <hip/hip_bf16.h>
#include <stdint.h>

#define TOKENS 8192
#define NOUT   4096
#define KIN    4096

#define BM 256
#define BN 256
#define BK 64
#define NT (KIN / BK)   // 64 K-tiles

typedef __attribute__((ext_vector_type(8))) short bf16x8;
typedef __attribute__((ext_vector_type(4))) float f32x4;

__device__ __forceinline__ uint32_t rotl32(uint32_t x, int r) {
  return (x << r) | (x >> (32 - r));
}

__device__ __forceinline__ uint16_t f2bf_rne(float f) {
  uint32_t u = __float_as_uint(f);
  u += 0x7FFFu + ((u >> 16) & 1u);
  return (uint16_t)(u >> 16);
}

// Threefry-2x32, 20 rounds — JAX PRNG core.
__device__ __forceinline__ void threefry2x32(uint32_t k0, uint32_t k1,
                                             uint32_t c0, uint32_t c1,
                                             uint32_t& o0, uint32_t& o1) {
  uint32_t ks2 = 0x1BD11BDAu ^ k0 ^ k1;
  uint32_t x0 = c0 + k0;
  uint32_t x1 = c1 + k1;
#define TFR(r) { x0 += x1; x1 = rotl32(x1, (r)); x1 ^= x0; }
  TFR(13) TFR(15) TFR(26) TFR(6)
  x0 += k1;  x1 += ks2 + 1u;
  TFR(17) TFR(29) TFR(16) TFR(24)
  x0 += ks2; x1 += k0 + 2u;
  TFR(13) TFR(15) TFR(26) TFR(6)
  x0 += k0;  x1 += k1 + 3u;
  TFR(17) TFR(29) TFR(16) TFR(24)
  x0 += k1;  x1 += ks2 + 4u;
  TFR(13) TFR(15) TFR(26) TFR(6)
  x0 += ks2; x1 += k0 + 5u;
#undef TFR
  o0 = x0; o1 = x1;
}

// Fused prep, interleaved 4:1 hydrate:convert (r13, verified win).
__global__ void prep_kernel(const float* __restrict__ x,
                            uint16_t* __restrict__ xb,
                            uint16_t* __restrict__ W,
                            const int* __restrict__ seed_ptr) {
  uint32_t b = blockIdx.x;
  uint32_t g = b / 5u, r = b % 5u;
  if (r < 4u) {
    uint32_t k1 = (uint32_t)(*seed_ptr);                  // key = (0, seed)
    uint32_t j = (g * 4u + r) * 256u + threadIdx.x;       // 0 .. 2^24-1
    uint32_t o0, o1;
    threefry2x32(0u, k1, 0u, j, o0, o1);
    uint32_t bits = o0 ^ o1;
    const float scale = 0.03125f;
    const float mn    = -0.015625f;
    float f = __uint_as_float((bits >> 9) | 0x3F800000u) - 1.0f;
    float v = fmaxf(mn, f * scale + mn);
    W[j] = f2bf_rne(v);
  } else {
    uint32_t base = (g * 256u + threadIdx.x) * 8u;
    f32x4 a = *(const f32x4*)(x + base);
    f32x4 c = *(const f32x4*)(x + base + 4);
    union { uint16_t u[8]; bf16x8 v; } rr;
    rr.u[0] = f2bf_rne(a[0]); rr.u[1] = f2bf_rne(a[1]);
    rr.u[2] = f2bf_rne(a[2]); rr.u[3] = f2bf_rne(a[3]);
    rr.u[4] = f2bf_rne(c[0]); rr.u[5] = f2bf_rne(c[1]);
    rr.u[6] = f2bf_rne(c[2]); rr.u[7] = f2bf_rne(c[3]);
    *(bf16x8*)(xb + base) = rr.v;
  }
}

// ---------------------------------------------------------------------------
// r13's verified 4-phase single-barrier schedule + r10 addressing diet.
// ROUND 17 FIX vs r16: restore the prologue s_barrier after VMW(6). Without
// it the first tile's P1 ds_reads raced other waves' prologue stages (each
// wave's VMW only covers its OWN loads; cross-wave LDS visibility needs the
// barrier) -> r16's absmax 41. Steady state was already safe: every later
// P1 read follows the previous P4's VMW(6)+barrier pair.
//
// Diet (r10-verified mechanics):
//   - 4 loop-carried stage pointers, +256 B per 2-tile iteration; per-call
//     offsets (128/256/384) fold into the global-load offset field.
//   - 8 precomputed ds_read byte-bases; s1 = s0 ^ 64 (exact: the OR operand
//     fq<<4 has bit6 clear, XOR carries through swzRd); every ds_read is
//     base + compile-time immediate (<= 22528, fits 16-bit ds offset).
// Schedule per K-tile (buf = kt&1) — IDENTICAL to r13:
//   P1: reads A0 s0/s1 + B0 s0/s1 (12, SB0-split) | stage A1(kt+1)->buf^1 |
//       barrier | LKW(6) 8·MFMA(0,0,s0) | LKW(0) 8·MFMA(0,0,s1)
//   P2: reads B1 s0/s1 (4) | barrier | LKW(2) 8·MF(0,1,s0) | LKW(0) 8·(s1)
//   P3: reads A1 s0/s1 (8, overwrites af) | stage A0+B0(kt+2)->buf |
//       barrier | LKW(4) 8·MF(1,1,s0) | LKW(0) 8·(s1)
//   P4: stage B1(kt+2)->buf | VMW(6) | barrier | 16·MF(1,0) (cached)
// WAR: single-barrier arrival implies the wave completed MFMA_{p-1} hence
// its LKW(0) — prior reads complete; stage slots have 2-phase lag.
// RAW @VMW(6): 6 newest = P3/P4's kt+2 loads => all of kt+1 landed.
// Operand set 64 VGPRs (af reused A0/A1) — fits the 128-VGPR non-acc
// budget (r15 lesson: acc = 128 regs of the 256 unified file at 2 w/SIMD).
// LDS swizzle: linear gload_lds dest + inverse-swizzled global source;
// reads XOR ((row&7)<<4); 0 bank conflicts (r5-r14).
// ---------------------------------------------------------------------------
__global__ __launch_bounds__(512, 2)
void gemm_bias_kernel(const uint16_t* __restrict__ A,   // x  bf16 [TOKENS][KIN]
                      const uint16_t* __restrict__ B,   // W  bf16 [NOUT][KIN]
                      const float* __restrict__ bias,
                      float* __restrict__ C) {
  __shared__ uint16_t smem[2][2][16384];   // [buf][A=0/B=1][32KB] = 128 KiB

  const int nwgn = NOUT / BN;                 // 16
  const int nwg  = (TOKENS / BM) * nwgn;      // 512 (divisible by 8)
  int bid = blockIdx.x;
  int cpx = nwg >> 3;
  int swzb = (bid & 7) * cpx + (bid >> 3);    // bijective XCD swizzle
  const int tm = (swzb / nwgn) * BM;
  const int tn = (swzb % nwgn) * BN;

  const int t    = threadIdx.x;
  const int lane = t & 63;
  const int wid  = t >> 6;       // 0..7
  const int wm   = wid >> 2;     // 0..1
  const int wn   = wid & 3;      // 0..3
  const int fr   = lane & 15;
  const int fq   = lane >> 4;

  const int swzRd = (lane & 7) << 4;                    // frag-read byte XOR
  const int lsw   = ((lane & 7) ^ (lane >> 3)) << 4;    // stage src byte offset

  // loop-carried stage source pointers (+256 B per 2-tile iteration)
  const char* sA  = (const char*)(A + (size_t)(tm + wid * 16 + (lane >> 3)) * KIN) + lsw;
  const char* sB  = (const char*)(B + (size_t)(tn + wid * 16 + (lane >> 3)) * KIN) + lsw;
  const char* sA1 = sA + (size_t)128 * KIN * 2;   // +128 rows (half 1)
  const char* sB1 = sB + (size_t)128 * KIN * 2;

  char* const smemB = (char*)&smem[0][0][0];
  char* const dstB  = smemB + wid * 2048 + lane * 16;

  // ds_read byte-bases (relative to smemB); s1 = s0 ^ 64 (exact)
  const int rA00 = (wm * 64 + fr) * 128 + ((fq << 4) ^ swzRd);  // A buf0 s0
  const int rA01 = rA00 ^ 64;
  const int rA10 = rA00 + 65536;
  const int rA11 = rA10 ^ 64;
  const int rB00 = 32768 + (wn * 32 + fr) * 128 + ((fq << 4) ^ swzRd);
  const int rB01 = rB00 ^ 64;
  const int rB10 = rB00 + 65536;
  const int rB11 = rB10 ^ 64;

  f32x4 acc[8][4] = {};
  bf16x8 af[2][4], bv0[2][2], bv1[2][2];

  auto stage2 = [&](const char* src, char* dst) {
    __builtin_amdgcn_global_load_lds(
        (const __attribute__((address_space(1))) void*)src,
        (__attribute__((address_space(3))) void*)dst, 16, 0, 0);
    __builtin_amdgcn_global_load_lds(
        (const __attribute__((address_space(1))) void*)(src + (size_t)8 * KIN * 2),
        (__attribute__((address_space(3))) void*)(dst + 1024), 16, 0, 0);
  };

#define VMW(N) asm volatile("s_waitcnt vmcnt(" #N ")" ::: "memory")
#define LKW(N) asm volatile("s_waitcnt lgkmcnt(" #N ")" ::: "memory")
#define SB0    __builtin_amdgcn_sched_barrier(0)
#define PRI(p) __builtin_amdgcn_s_setprio(p)

// 4 ds_read_b128: af[S][0..3] from base BASE (+ i*2048 immediates)
#define RD_A4(BASE, S)                                                         \
    _Pragma("unroll")                                                          \
    for (int i_ = 0; i_ < 4; ++i_)                                             \
      af[S][i_] = *(const bf16x8*)(smemB + (BASE) + i_ * 2048);

// 2 ds_read_b128: BV[S][0..1] from base BASE
#define RD_B2(BASE, BV, S)                                                     \
    _Pragma("unroll")                                                          \
    for (int j_ = 0; j_ < 2; ++j_)                                             \
      BV[S][j_] = *(const bf16x8*)(smemB + (BASE) + j_ * 2048);

// 8 MFMA: k-group S of quadrant (MH,NH)
#define MF8(MH, NH, BV, S)                                                     \
    _Pragma("unroll")                                                          \
    for (int i_ = 0; i_ < 4; ++i_)                                             \
      _Pragma("unroll")                                                        \
      for (int j_ = 0; j_ < 2; ++j_)                                           \
        acc[(MH) * 4 + i_][(NH) * 2 + j_] =                                    \
            __builtin_amdgcn_mfma_f32_16x16x32_bf16(                           \
                af[S][i_], BV[S][j_], acc[(MH) * 4 + i_][(NH) * 2 + j_],       \
                0, 0, 0);

  // OFF1 = byte k-offset of kt+1; OFF2 = kt+2 (relative to pointers).
  // MODE: 0 steady; 1 = kt62 (stage A1(63) only, VMW(0)@P4); 2 = kt63.
#define KTILE(BUF, OFF1, OFF2, MODE)                                           \
  {                                                                            \
    /* P1: reads A0 + B0 (s0 | s1), stage A1(kt+1)->buf^1 */                   \
    RD_A4((BUF) ? rA10 : rA00, 0) RD_B2((BUF) ? rB10 : rB00, bv0, 0)           \
    SB0;                                                                       \
    RD_A4((BUF) ? rA11 : rA01, 1) RD_B2((BUF) ? rB11 : rB01, bv0, 1)           \
    if ((MODE) <= 1) stage2(sA1 + (OFF1),                                      \
                            dstB + ((BUF) ^ 1) * 65536 + 16384);               \
    __builtin_amdgcn_s_barrier();                                              \
    LKW(6); SB0; PRI(1); MF8(0, 0, bv0, 0)                                     \
    LKW(0); SB0; MF8(0, 0, bv0, 1) PRI(0);                                     \
    /* P2: reads B1 (s0 | s1) */                                               \
    RD_B2(((BUF) ? rB10 : rB00) + 16384, bv1, 0)                               \
    SB0;                                                                       \
    RD_B2(((BUF) ? rB11 : rB01) + 16384, bv1, 1)                               \
    __builtin_amdgcn_s_barrier();                                              \
    LKW(2); SB0; PRI(1); MF8(0, 1, bv1, 0)                                     \
    LKW(0); SB0; MF8(0, 1, bv1, 1) PRI(0);                                     \
    /* P3: reads A1 (s0 | s1, overwrites af), stage A0+B0(kt+2)->buf */        \
    RD_A4(((BUF) ? rA10 : rA00) + 16384, 0)                                    \
    SB0;                                                                       \
    RD_A4(((BUF) ? rA11 : rA01) + 16384, 1)                                    \
    if ((MODE) == 0) { stage2(sA + (OFF2), dstB + (BUF) * 65536);              \
                       stage2(sB + (OFF2), dstB + (BUF) * 65536 + 32768); }    \
    __builtin_amdgcn_s_barrier();                                              \
    LKW(4); SB0; PRI(1); MF8(1, 1, bv1, 0)                                     \
    LKW(0); SB0; MF8(1, 1, bv1, 1) PRI(0);                                     \
    /* P4: stage B1(kt+2)->buf | the ONE vm wait | barrier | cached MFMA */    \
    if ((MODE) == 0) stage2(sB1 + (OFF2), dstB + (BUF) * 65536 + 49152);       \
    if ((MODE) == 0) { VMW(6); } else if ((MODE) == 1) { VMW(0); }             \
    __builtin_amdgcn_s_barrier();                                              \
    SB0; PRI(1); MF8(1, 0, bv0, 0) MF8(1, 0, bv0, 1) PRI(0);                   \
  }

  // Prologue: kt0 all 4 halves -> buf0, kt1's A0,B0,B1 -> buf1; VMW(6)
  // (14 outstanding -> the 8 oldest = all of kt0 landed) THEN s_barrier
  // to publish cross-wave BEFORE the first KTILE's P1 reads (r16 bug fix).
  stage2(sA,        dstB);                    // A0 kt0
  stage2(sB,        dstB + 32768);            // B0 kt0
  stage2(sA1,       dstB + 16384);            // A1 kt0
  stage2(sB1,       dstB + 49152);            // B1 kt0
  stage2(sA  + 128, dstB + 65536);            // A0 kt1
  stage2(sB  + 128, dstB + 65536 + 32768);    // B0 kt1
  stage2(sB1 + 128, dstB + 65536 + 49152);    // B1 kt1
  VMW(6);
  __builtin_amdgcn_s_barrier();

  for (int it = 0; it < (NT - 2) / 2; ++it) {   // tiles 0..61
    KTILE(0, 128, 256, 0)
    KTILE(1, 256, 384, 0)
    sA += 256; sB += 256; sA1 += 256; sB1 += 256;
  }
  KTILE(0, 128, 0, 1)   // kt62: stage A1(63) only, drain
  KTILE(1, 0, 0, 2)     // kt63

#undef KTILE
#undef MF8
#undef RD_B2
#undef RD_A4
#undef PRI
#undef SB0
#undef LKW
#undef VMW

  // Epilogue: D row = fq*4 + rr, col = fr (m89/m91-verified), fused bias.
#pragma unroll
  for (int nj = 0; nj < 4; ++nj) {
    const int nh = nj >> 1, j = nj & 1;
    const int col = tn + wn * 32 + nh * 128 + j * 16 + fr;
    const float bvs = bias[col];
#pragma unroll
    for (int mi = 0; mi < 8; ++mi) {
      const int mh = mi >> 2, i = mi & 3;
      const int row0 = tm + wm * 64 + mh * 128 + i * 16 + fq * 4;
#pragma unroll
      for (int rr = 0; rr < 4; ++rr)
        C[(size_t)(row0 + rr) * NOUT + col] = acc[mi][nj][rr] + bvs;
    }
  }
}

extern "C" void kernel_launch(void* const* d_in, const int* in_sizes, int n_in,
                              void* d_out, int out_size, void* d_ws, size_t ws_size,
                              hipStream_t stream) {
  const float* x    = (const float*)d_in[0];   // [8192][4096] fp32
  const float* bias = (const float*)d_in[1];   // [4096] fp32
  const int*   seed = (const int*)d_in[2];     // [1] int
  float* y = (float*)d_out;                    // [8192][4096] fp32

  // workspace: W bf16 (32 MB) | x bf16 (64 MB) — 96 MB, proven available
  uint16_t* Wb = (uint16_t*)d_ws;
  uint16_t* Xb = Wb + (size_t)NOUT * KIN;

  prep_kernel<<<81920, 256, 0, stream>>>(x, Xb, Wb, seed);

  const int grid = (TOKENS / BM) * (NOUT / BN);   // 512
  gemm_bias_kernel<<<grid, 512, 0, stream>>>(Xb, Wb, bias, y);
}